// Round 11
// baseline (429.951 us; speedup 1.0000x reference)
//
#include <hip/hip_runtime.h>
#include <math.h>

#define BB 8
#define NN 1024
#define DD 1024
#define HH 16
#define SS 64
#define BH (BB*HH)

typedef _Float16 half8 __attribute__((ext_vector_type(8)));
typedef _Float16 half4v __attribute__((ext_vector_type(4)));
typedef float floatx4 __attribute__((ext_vector_type(4)));

#define MFMA16(A, B, C) __builtin_amdgcn_mfma_f32_16x16x32_f16((A), (B), (C), 0, 0, 0)

// async global -> LDS, 16B per lane (dest must be wave-uniform base + lane*16)
__device__ __forceinline__ void gload16(const _Float16* g, _Float16* l) {
    __builtin_amdgcn_global_load_lds(
        (const __attribute__((address_space(1))) void*)g,
        (__attribute__((address_space(3))) void*)l,
        16, 0, 0);
}

// ---------------- Pre-pass: split X into fp16 hi/lo ----------------
__global__ __launch_bounds__(256) void split_x(
    const float* __restrict__ X, _Float16* __restrict__ Xh, _Float16* __restrict__ Xl)
{
    int idx = (blockIdx.x * 256 + threadIdx.x) * 4;
    float4 x4 = *(const float4*)(X + idx);
    float xs[4] = {x4.x, x4.y, x4.z, x4.w};
    half4v h, l;
    #pragma unroll
    for (int i = 0; i < 4; i++) {
        _Float16 hi = (_Float16)xs[i];
        h[i] = hi;
        l[i] = (_Float16)(xs[i] - (float)hi);
    }
    *(half4v*)(Xh + idx) = h;
    *(half4v*)(Xl + idx) = l;
}

// ---------------- Pre-pass: split + transpose W ----------------
__global__ __launch_bounds__(256) void split_wt(
    const float* __restrict__ W, _Float16* __restrict__ Wth, _Float16* __restrict__ Wtl)
{
    __shared__ float tile[64][68];
    const int hc = blockIdx.x, d0 = blockIdx.y * 64;
    const int t = threadIdx.x;
    {
        int i = t >> 2, sq = (t & 3) * 16;
        const float* src = W + ((size_t)hc * DD + d0 + i) * SS + sq;
        #pragma unroll
        for (int u = 0; u < 4; u++) {
            float4 v = *(const float4*)(src + 4 * u);
            tile[i][sq + 4 * u + 0] = v.x; tile[i][sq + 4 * u + 1] = v.y;
            tile[i][sq + 4 * u + 2] = v.z; tile[i][sq + 4 * u + 3] = v.w;
        }
    }
    __syncthreads();
    {
        int s = t >> 2, jq = (t & 3) * 16;
        _Float16 hbuf[16], lbuf[16];
        #pragma unroll
        for (int u = 0; u < 16; u++) {
            float x = tile[jq + u][s];
            _Float16 hi = (_Float16)x;
            hbuf[u] = hi;
            lbuf[u] = (_Float16)(x - (float)hi);
        }
        size_t off = (size_t)hc * SS * DD + (size_t)s * DD + d0 + jq;
        *(half8*)(Wth + off)     = *(half8*)(hbuf);
        *(half8*)(Wth + off + 8) = *(half8*)(hbuf + 8);
        *(half8*)(Wtl + off)     = *(half8*)(lbuf);
        *(half8*)(Wtl + off + 8) = *(half8*)(lbuf + 8);
    }
}

// ---------------- Kernel 1: QKV projection, m97-style LDS-staged GEMM ------
// (unchanged — at ~88% of the m97-structure ceiling; do not touch)
__global__ __launch_bounds__(256, 2) void qkv_mfma(
    const _Float16* __restrict__ Xh, const _Float16* __restrict__ Xl,
    const _Float16* __restrict__ Wth, const _Float16* __restrict__ Wtl,
    _Float16* __restrict__ Qh, _Float16* __restrict__ Ql,
    _Float16* __restrict__ Kh, _Float16* __restrict__ Kl,
    _Float16* __restrict__ Vt)
{
    const int flat = blockIdx.y * 64 + blockIdx.x;
    const int swz  = (flat & 7) * 192 + (flat >> 3);
    const int bx = swz & 63;       // token tile (0..63)
    const int by = swz >> 6;       // hc-pair  (0..23)
    const int hc0 = by * 2;
    const int r0  = bx * 128;

    const int tid = threadIdx.x;
    const int wave = tid >> 6, lane = tid & 63;
    const int l16 = lane & 15, quad = lane >> 4;
    const int wr = wave >> 1, wc = wave & 1;   // 2x2 wave grid, 64x64 each

    __shared__ _Float16 sAh[128 * 32];   // 8 KB each, 32 KB total
    __shared__ _Float16 sAl[128 * 32];
    __shared__ _Float16 sBh[128 * 32];
    __shared__ _Float16 sBl[128 * 32];

    floatx4 acc[4][4];
    #pragma unroll
    for (int i = 0; i < 4; i++)
        #pragma unroll
        for (int j = 0; j < 4; j++) acc[i][j] = (floatx4){0.f, 0.f, 0.f, 0.f};

    const _Float16* Ab_h = Xh  + (size_t)r0 * DD;
    const _Float16* Ab_l = Xl  + (size_t)r0 * DD;
    const _Float16* Bb_h = Wth + (size_t)hc0 * SS * DD;
    const _Float16* Bb_l = Wtl + (size_t)hc0 * SS * DD;

    for (int k0 = 0; k0 < DD; k0 += 32) {
        #pragma unroll
        for (int i = 0; i < 2; i++) {
            const int g = tid + 256 * i;
            const int row = g >> 2, kc = (g & 3) * 8;
            const size_t go = (size_t)row * DD + k0 + kc;
            gload16(Ab_h + go, &sAh[g * 8]);
            gload16(Ab_l + go, &sAl[g * 8]);
            gload16(Bb_h + go, &sBh[g * 8]);
            gload16(Bb_l + go, &sBl[g * 8]);
        }
        __syncthreads();

        half8 Ah[4], Al[4], Bh[4], Bl[4];
        #pragma unroll
        for (int t = 0; t < 4; t++) {
            const int ar = wr * 64 + 16 * t + l16;
            const int br = wc * 64 + 16 * t + l16;
            Ah[t] = *(const half8*)&sAh[ar * 32 + quad * 8];
            Al[t] = *(const half8*)&sAl[ar * 32 + quad * 8];
            Bh[t] = *(const half8*)&sBh[br * 32 + quad * 8];
            Bl[t] = *(const half8*)&sBl[br * 32 + quad * 8];
        }
        #pragma unroll
        for (int i = 0; i < 4; i++)
            #pragma unroll
            for (int j = 0; j < 4; j++)
                acc[i][j] = MFMA16(Ah[i], Bh[j], acc[i][j]);
        #pragma unroll
        for (int i = 0; i < 4; i++)
            #pragma unroll
            for (int j = 0; j < 4; j++)
                acc[i][j] = MFMA16(Ah[i], Bl[j], acc[i][j]);
        #pragma unroll
        for (int i = 0; i < 4; i++)
            #pragma unroll
            for (int j = 0; j < 4; j++)
                acc[i][j] = MFMA16(Al[i], Bh[j], acc[i][j]);
        __syncthreads();
    }

    const int hc = hc0 + wc;
    const int h = hc / 3, c = hc % 3;
    const int rowbase = r0 + wr * 64;
    if (c == 2) {
        #pragma unroll
        for (int i = 0; i < 4; i++)
            #pragma unroll
            for (int j = 0; j < 4; j++) {
                int tok0 = rowbase + 16 * i + 4 * quad;
                int b = tok0 >> 10, n0 = tok0 & 1023;
                half4v pk;
                #pragma unroll
                for (int r = 0; r < 4; r++) pk[r] = (_Float16)acc[i][j][r];
                *(half4v*)(Vt + ((size_t)(b * HH + h) * SS + 16 * j + l16) * NN + n0) = pk;
            }
    } else {
        _Float16* Ph = (c == 0) ? Qh : Kh;
        _Float16* Pl = (c == 0) ? Ql : Kl;
        #pragma unroll
        for (int i = 0; i < 4; i++)
            #pragma unroll
            for (int j = 0; j < 4; j++)
                #pragma unroll
                for (int r = 0; r < 4; r++) {
                    int tok = rowbase + 16 * i + 4 * quad + r;
                    int b = tok >> 10, n = tok & 1023;
                    float v = acc[i][j][r];
                    _Float16 vh = (_Float16)v;
                    _Float16 vl = (_Float16)(v - (float)vh);
                    size_t off = ((size_t)(b * HH + h) * NN + n) * SS + 16 * j + l16;
                    Ph[off] = vh; Pl[off] = vl;
                }
    }
}

// ---------------- Kernel 2: MFMA flash attention, swapped QK^T -------------
// R10 = R9 (R5 + setprio, attn 186->174 per-dispatch) with ONE change:
// 512-thread blocks (8 waves, 256 q-rows/block), grid (128, 4).
// Per-wave code identical (g=2, 32 rows/wave; R7 proved per-WAVE row
// doubling costs VGPR — this doubles rows per BLOCK). Effects:
//  - LDS = Ms 4 + K/V 24 + Plds[8][32][72] 36 = 64 KB -> 2 blocks x 8 waves
//    = 16 waves/CU (was 12, +33% TLP; VGPR ~112 allows 4 waves/SIMD)
//  - K/V staging per output halves (one stage serves 256 rows; 1 granule/thr)
//  - grid 512 = exactly 2 blocks/CU, zero tail.
// Arithmetic per q-row unchanged -> bit-identical output.
__global__ __launch_bounds__(512) void attn_mfma(
    const _Float16* __restrict__ Qh, const _Float16* __restrict__ Ql,
    const _Float16* __restrict__ Kh, const _Float16* __restrict__ Kl,
    const _Float16* __restrict__ Vt,
    const float* __restrict__ mask,
    float* __restrict__ out)
{
    const int bh = blockIdx.x, qt = blockIdx.y;   // qt in 0..3
    const int b = bh >> 4, h = bh & 15;
    const int tid = threadIdx.x;
    const int wave = tid >> 6, lane = tid & 63;   // wave in 0..7
    const int l16 = lane & 15, quad = lane >> 4;

    __shared__ float Ms[NN];                 //  4 KB
    __shared__ _Float16 KhS[64 * 64];        //  8 KB
    __shared__ _Float16 KlS[64 * 64];        //  8 KB
    __shared__ _Float16 VS [64 * 64];        //  8 KB
    __shared__ _Float16 Plds[8][32][72];     // 36 KB   total 64 KB -> 2 blk/CU

    *(float2*)&Ms[tid * 2] = *(const float2*)(mask + b * NN + tid * 2);

    // granule g = tid in [0,512): row=g>>3, slot col=g&7,
    // source col c=(g&7)^(row&7)  (XOR swizzle realized by permuting source)
    half8 G[3];
    auto stage_load = [&](int kt_) {
        int g = tid;
        int row = g >> 3;
        int c = (g & 7) ^ (row & 7);
        size_t ko = ((size_t)bh * NN + kt_ * 64 + row) * SS + c * 8;
        G[0] = *(const half8*)(Kh + ko);
        G[1] = *(const half8*)(Kl + ko);
        G[2] = *(const half8*)(Vt + ((size_t)bh * SS + row) * NN
                               + (size_t)kt_ * 64 + c * 8);
    };
    auto stage_store = [&]() {
        int g = tid;
        *(half8*)&KhS[g * 8] = G[0];
        *(half8*)&KlS[g * 8] = G[1];
        *(half8*)&VS [g * 8] = G[2];
    };

    stage_load(0);
    stage_store();
    __syncthreads();     // Ms + buf ready

    const int qrow0 = qt * 256 + wave * 32;
    half8 Aqh[2][2], Aql[2][2];
    #pragma unroll
    for (int g = 0; g < 2; g++) {
        const size_t qbase = ((size_t)bh * NN + qrow0 + 16 * g + l16) * SS + quad * 8;
        Aqh[g][0] = *(const half8*)(Qh + qbase);
        Aqh[g][1] = *(const half8*)(Qh + qbase + 32);
        Aql[g][0] = *(const half8*)(Ql + qbase);
        Aql[g][1] = *(const half8*)(Ql + qbase + 32);
    }

    // per-lane state for q-row = qrow0 + 16*g + l16
    float qm[2], m_old[2], l_sum[2];
    floatx4 accO[2][4];
    #pragma unroll
    for (int g = 0; g < 2; g++) {
        qm[g] = Ms[qrow0 + 16 * g + l16];
        m_old[g] = -3.0e38f;
        l_sum[g] = 0.f;
        #pragma unroll
        for (int j = 0; j < 4; j++) accO[g][j] = (floatx4){0.f, 0.f, 0.f, 0.f};
    }

    const int sw = l16 & 7;

    for (int kt = 0; kt < 16; kt++) {
        if (kt < 15) stage_load(kt + 1);   // in flight during compute below

        // ---- S^T = K Q^T (fp16x3): same frags, swapped operand roles ----
        floatx4 accS[2][4];
        #pragma unroll
        for (int g = 0; g < 2; g++)
            #pragma unroll
            for (int jt = 0; jt < 4; jt++) accS[g][jt] = (floatx4){0.f, 0.f, 0.f, 0.f};
        __builtin_amdgcn_s_setprio(1);
        #pragma unroll
        for (int jt = 0; jt < 4; jt++) {
            const int rowK = jt * 16 + l16;
            const _Float16* krh = &KhS[rowK * 64];
            const _Float16* krl = &KlS[rowK * 64];
            half8 Bh0 = *(const half8*)&krh[((quad    ) ^ sw) * 8];
            half8 Bh1 = *(const half8*)&krh[((quad + 4) ^ sw) * 8];
            half8 Bl0 = *(const half8*)&krl[((quad    ) ^ sw) * 8];
            half8 Bl1 = *(const half8*)&krl[((quad + 4) ^ sw) * 8];
            #pragma unroll
            for (int g = 0; g < 2; g++) {
                accS[g][jt] = MFMA16(Bh0, Aqh[g][0], accS[g][jt]);
                accS[g][jt] = MFMA16(Bh1, Aqh[g][1], accS[g][jt]);
                accS[g][jt] = MFMA16(Bl0, Aqh[g][0], accS[g][jt]);
                accS[g][jt] = MFMA16(Bl1, Aqh[g][1], accS[g][jt]);
                accS[g][jt] = MFMA16(Bh0, Aql[g][0], accS[g][jt]);
                accS[g][jt] = MFMA16(Bh1, Aql[g][1], accS[g][jt]);
            }
        }
        __builtin_amdgcn_s_setprio(0);
        // accS[g][jt][r] = S[q = qrow0+16g+l16][k = kt*64 + jt*16 + quad*4 + r]

        // ---- literal fp32 mask penalty (k-cols contiguous: float4 loads) ----
        float km[4][4];
        #pragma unroll
        for (int jt = 0; jt < 4; jt++) {
            float4 k4 = *(const float4*)&Ms[kt * 64 + jt * 16 + quad * 4];
            km[jt][0] = k4.x; km[jt][1] = k4.y; km[jt][2] = k4.z; km[jt][3] = k4.w;
        }
        #pragma unroll
        for (int g = 0; g < 2; g++)
            #pragma unroll
            for (int jt = 0; jt < 4; jt++)
                #pragma unroll
                for (int r = 0; r < 4; r++)
                    accS[g][jt][r] -= 1.0e8f * (1.0f - qm[g] * km[jt][r]);

        // ---- online softmax: lane-local row, 2 shuffles per reduce ----
        #pragma unroll
        for (int g = 0; g < 2; g++) {
            float a0 = fmaxf(fmaxf(accS[g][0][0], accS[g][0][1]),
                             fmaxf(accS[g][0][2], accS[g][0][3]));
            float a1 = fmaxf(fmaxf(accS[g][1][0], accS[g][1][1]),
                             fmaxf(accS[g][1][2], accS[g][1][3]));
            float a2 = fmaxf(fmaxf(accS[g][2][0], accS[g][2][1]),
                             fmaxf(accS[g][2][2], accS[g][2][3]));
            float a3 = fmaxf(fmaxf(accS[g][3][0], accS[g][3][1]),
                             fmaxf(accS[g][3][2], accS[g][3][3]));
            float mt = fmaxf(fmaxf(a0, a1), fmaxf(a2, a3));
            mt = fmaxf(mt, __shfl_xor(mt, 16, 64));
            mt = fmaxf(mt, __shfl_xor(mt, 32, 64));
            float mn = fmaxf(m_old[g], mt);

            float sj[4];
            #pragma unroll
            for (int jt = 0; jt < 4; jt++) {
                float p0 = __expf(accS[g][jt][0] - mn);
                float p1 = __expf(accS[g][jt][1] - mn);
                float p2 = __expf(accS[g][jt][2] - mn);
                float p3 = __expf(accS[g][jt][3] - mn);
                accS[g][jt][0] = p0; accS[g][jt][1] = p1;
                accS[g][jt][2] = p2; accS[g][jt][3] = p3;
                sj[jt] = (p0 + p1) + (p2 + p3);
            }
            float ls = (sj[0] + sj[1]) + (sj[2] + sj[3]);
            ls += __shfl_xor(ls, 16, 64);
            ls += __shfl_xor(ls, 32, 64);

            // defer-rescale: if no lane's max grew, mn == m_old for every
            // lane, alpha == __expf(0) == 1.0 exactly -> skip is bit-identical.
            if (__any(mt > m_old[g])) {
                float alpha = __expf(m_old[g] - mn);
                m_old[g] = mn;
                l_sum[g] = l_sum[g] * alpha + ls;
                float alphaO[4];
                #pragma unroll
                for (int r = 0; r < 4; r++)
                    alphaO[r] = __shfl(alpha, quad * 4 + r, 64);
                #pragma unroll
                for (int j = 0; j < 4; j++)
                    #pragma unroll
                    for (int r = 0; r < 4; r++)
                        accO[g][j][r] *= alphaO[r];
            } else {
                l_sum[g] = l_sum[g] + ls;
            }

            // P -> LDS: k-contiguous half4v packs, row = q, col = k
            #pragma unroll
            for (int jt = 0; jt < 4; jt++) {
                half4v pk;
                #pragma unroll
                for (int r = 0; r < 4; r++) pk[r] = (_Float16)accS[g][jt][r];
                *(half4v*)&Plds[wave][16 * g + l16][jt * 16 + quad * 4] = pk;
            }
        }

        // ---- O += P V (A = P rows q, k-chunk quad*8; B = V from LDS) ----
        __builtin_amdgcn_s_setprio(1);
        #pragma unroll
        for (int ks = 0; ks < 2; ks++) {
            half8 Ap[2];
            #pragma unroll
            for (int g = 0; g < 2; g++)
                Ap[g] = *(const half8*)&Plds[wave][16 * g + l16][ks * 32 + quad * 8];
            #pragma unroll
            for (int j = 0; j < 4; j++) {
                half8 Bv = *(const half8*)&VS[(j * 16 + l16) * 64
                                              + (((ks * 4 + quad) ^ sw) * 8)];
                #pragma unroll
                for (int g = 0; g < 2; g++)
                    accO[g][j] = MFMA16(Ap[g], Bv, accO[g][j]);
            }
        }
        __builtin_amdgcn_s_setprio(0);

        if (kt < 15) {
            __syncthreads();     // all waves done reading KhS/KlS/VS
            stage_store();       // waits in-flight loads, fills buf
            __syncthreads();     // buf ready
        }
    }

    // ---- epilogue: out[b, n, s*16 + h]; l_sum lives at lane l16 = q ----
    #pragma unroll
    for (int g = 0; g < 2; g++) {
        float inv[4];
        #pragma unroll
        for (int r = 0; r < 4; r++)
            inv[r] = 1.f / __shfl(l_sum[g], quad * 4 + r, 64);
        #pragma unroll
        for (int r = 0; r < 4; r++) {
            int qrow = qrow0 + 16 * g + quad * 4 + r;
            #pragma unroll
            for (int j = 0; j < 4; j++)
                out[((size_t)(b * NN + qrow)) * (SS * HH) + (j * 16 + l16) * HH + h] =
                    accO[g][j][r] * inv[r];
        }
    }
}

// ================= fp32 fallback path (R2, known-good) =================
__global__ __launch_bounds__(256) void qkv_kernel(
    const float* __restrict__ X, const float* __restrict__ W, float* __restrict__ qkv)
{
    const int ttile = blockIdx.x;
    const int hc    = blockIdx.y;
    const int h     = hc / 3, c = hc % 3;
    const int tid = threadIdx.x;
    const int tx = tid & 15, ty = tid >> 4;
    __shared__ float As[32][68];
    __shared__ float Bs[32][68];
    const float* Wb = W + (size_t)hc * DD * SS;
    const int row0 = ttile * 64;
    float acc[4][4];
    #pragma unroll
    for (int i = 0; i < 4; i++)
        #pragma unroll
        for (int j = 0; j < 4; j++) acc[i][j] = 0.f;
    for (int k0 = 0; k0 < DD; k0 += 32) {
        #pragma unroll
        for (int l = 0; l < 2; l++) {
            int i = tid + l * 256;
            int r = i >> 3;
            int kq = (i & 7) * 4;
            float4 x4 = *(const float4*)(X + (size_t)(row0 + r) * DD + k0 + kq);
            As[kq + 0][r] = x4.x; As[kq + 1][r] = x4.y;
            As[kq + 2][r] = x4.z; As[kq + 3][r] = x4.w;
        }
        #pragma unroll
        for (int l = 0; l < 2; l++) {
            int i = tid + l * 256;
            int kr = i >> 4;
            int sq = (i & 15) * 4;
            *(float4*)&Bs[kr][sq] = *(const float4*)(Wb + (size_t)(k0 + kr) * SS + sq);
        }
        __syncthreads();
        #pragma unroll
        for (int kk = 0; kk < 32; kk++) {
            float4 a4 = *(const float4*)&As[kk][ty * 4];
            float4 b4 = *(const float4*)&Bs[kk][tx * 4];
            float a[4] = {a4.x, a4.y, a4.z, a4.w};
            float bb[4] = {b4.x, b4.y, b4.z, b4.w};
            #pragma unroll
            for (int i = 0; i < 4; i++)
                #pragma unroll
                for (int j = 0; j < 4; j++)
                    acc[i][j] = fmaf(a[i], bb[j], acc[i][j]);
        }
        __syncthreads();
    }
    float* outp = qkv + (size_t)c * BH * NN * SS;
    #pragma unroll
    for (int i = 0; i < 4; i++) {
        int tg = row0 + ty * 4 + i;
        int b = tg >> 10, n = tg & 1023;
        float4 v4 = make_float4(acc[i][0], acc[i][1], acc[i][2], acc[i][3]);
        *(float4*)(outp + ((size_t)(b * HH + h) * NN + n) * SS + tx * 4) = v4;
    }
}

__global__ __launch_bounds__(256) void attn_kernel(
    const float* __restrict__ qkv,
    const float* __restrict__ mask,
    float* __restrict__ out)
{
    const int qt = blockIdx.x, h = blockIdx.y, b = blockIdx.z;
    const int tid = threadIdx.x;
    const int tx = tid & 15, ty = tid >> 4;
    const int bh = b * HH + h;
    const float* Q = qkv + (size_t)bh * NN * SS;
    const float* K = qkv + (size_t)BH * NN * SS + (size_t)bh * NN * SS;
    const float* V = qkv + 2 * (size_t)BH * NN * SS + (size_t)bh * NN * SS;

    __shared__ float QsT[64][68];
    __shared__ float KsT[64][68];
    __shared__ float Vs [64][68];
    __shared__ float PsT[64][68];
    __shared__ float Ms[NN];

    {
        float4 mm = *(const float4*)(mask + b * NN + tid * 4);
        *(float4*)&Ms[tid * 4] = mm;
    }
    #pragma unroll
    for (int l = 0; l < 4; l++) {
        int i = tid + l * 256;
        int r = i >> 4, sq = (i & 15) * 4;
        float4 x4 = *(const float4*)(Q + (size_t)(qt * 64 + r) * SS + sq);
        QsT[sq + 0][r] = x4.x; QsT[sq + 1][r] = x4.y;
        QsT[sq + 2][r] = x4.z; QsT[sq + 3][r] = x4.w;
    }
    __syncthreads();

    float m_old[4], l_sum[4], O[4][4], qm[4];
    #pragma unroll
    for (int i = 0; i < 4; i++) {
        qm[i] = Ms[qt * 64 + ty * 4 + i];
        m_old[i] = -3.0e38f; l_sum[i] = 0.f;
        #pragma unroll
        for (int j = 0; j < 4; j++) O[i][j] = 0.f;
    }

    for (int kt = 0; kt < 16; kt++) {
        #pragma unroll
        for (int l = 0; l < 4; l++) {
            int i = tid + l * 256;
            int r = i >> 4, sq = (i & 15) * 4;
            float4 k4 = *(const float4*)(K + (size_t)(kt * 64 + r) * SS + sq);
            KsT[sq + 0][r] = k4.x; KsT[sq + 1][r] = k4.y;
            KsT[sq + 2][r] = k4.z; KsT[sq + 3][r] = k4.w;
            float4 v4 = *(const float4*)(V + (size_t)(kt * 64 + r) * SS + sq);
            *(float4*)&Vs[r][sq] = v4;
        }
        __syncthreads();

        float sc[4][4];
        #pragma unroll
        for (int i = 0; i < 4; i++)
            #pragma unroll
            for (int j = 0; j < 4; j++) sc[i][j] = 0.f;
        #pragma unroll 8
        for (int s = 0; s < 64; s++) {
            float4 a4 = *(const float4*)&QsT[s][ty * 4];
            float4 b4 = *(const float4*)&KsT[s][tx * 4];
            float a[4] = {a4.x, a4.y, a4.z, a4.w};
            float bb[4] = {b4.x, b4.y, b4.z, b4.w};
            #pragma unroll
            for (int i = 0; i < 4; i++)
                #pragma unroll
                for (int j = 0; j < 4; j++)
                    sc[i][j] = fmaf(a[i], bb[j], sc[i][j]);
        }
        float km[4];
        #pragma unroll
        for (int j = 0; j < 4; j++) km[j] = Ms[kt * 64 + tx * 4 + j];
        #pragma unroll
        for (int i = 0; i < 4; i++)
            #pragma unroll
            for (int j = 0; j < 4; j++) {
                float pen = 1.0e8f * (1.0f - qm[i] * km[j]);
                sc[i][j] = sc[i][j] - pen;
            }

        #pragma unroll
        for (int i = 0; i < 4; i++) {
            float mt = fmaxf(fmaxf(sc[i][0], sc[i][1]), fmaxf(sc[i][2], sc[i][3]));
            #pragma unroll
            for (int off = 1; off < 16; off <<= 1)
                mt = fmaxf(mt, __shfl_xor(mt, off, 64));
            float mn = fmaxf(m_old[i], mt);
            float alpha = __expf(m_old[i] - mn);
            float p[4];
            #pragma unroll
            for (int j = 0; j < 4; j++) p[j] = __expf(sc[i][j] - mn);
            float ls = (p[0] + p[1]) + (p[2] + p[3]);
            #pragma unroll
            for (int off = 1; off < 16; off <<= 1)
                ls += __shfl_xor(ls, off, 64);
            l_sum[i] = l_sum[i] * alpha + ls;
            m_old[i] = mn;
            #pragma unroll
            for (int j = 0; j < 4; j++) {
                O[i][j] *= alpha;
                PsT[tx * 4 + j][ty * 4 + i] = p[j];
            }
        }
        __syncthreads();

        #pragma unroll 8
        for (int kj = 0; kj < 64; kj++) {
            float4 p4 = *(const float4*)&PsT[kj][ty * 4];
            float4 v4 = *(const float4*)&Vs[kj][tx * 4];
            float p[4] = {p4.x, p4.y, p4.z, p4.w};
            float vv[4] = {v4.x, v4.y, v4.z, v4.w};
            #pragma unroll
            for (int i = 0; i < 4; i++)
                #pragma unroll
                for (int j = 0; j < 4; j++)
                    O[i][j] = fmaf(p[i], vv[j], O[i][j]);
        }
        __syncthreads();
    }

    #pragma unroll
    for (int i = 0; i < 4; i++) {
        int qrow = qt * 64 + ty * 4 + i;
        float inv = 1.f / l_sum[i];
        #pragma unroll
        for (int j = 0; j < 4; j++) {
            int s = tx * 4 + j;
            out[((size_t)(b * NN + qrow)) * (SS * HH) + s * HH + h] = O[i][j] * inv;
        }
    }
}

extern "C" void kernel_launch(void* const* d_in, const int* in_sizes, int n_in,
                              void* d_out, int out_size, void* d_ws, size_t ws_size,
                              hipStream_t stream) {
    const float* X    = (const float*)d_in[0];   // [8,1024,1024]
    const float* mask = (const float*)d_in[1];   // [8,1024]
    const float* W    = (const float*)d_in[2];   // [16,3,1024,64]
    float* out = (float*)d_out;

    const size_t x_elems  = (size_t)BB * NN * DD;       // 8,388,608
    const size_t w_elems  = (size_t)HH * 3 * SS * DD;   // 3,145,728
    const size_t qk_elems = (size_t)BH * NN * SS;       // 8,388,608
    const size_t need_fast = (2 * x_elems + 2 * w_elems + 5 * qk_elems) * sizeof(_Float16); // ~130 MB

    if (ws_size >= need_fast) {
        _Float16* Xh  = (_Float16*)d_ws;
        _Float16* Xl  = Xh  + x_elems;
        _Float16* Wth = Xl  + x_elems;
        _Float16* Wtl = Wth + w_elems;
        _Float16* Qh  = Wtl + w_elems;
        _Float16* Ql  = Qh  + qk_elems;
        _Float16* Kh  = Ql  + qk_elems;
        _Float16* Kl  = Kh  + qk_elems;
        _Float16* Vt  = Kl  + qk_elems;

        split_x<<<dim3((unsigned)(x_elems / 1024)), dim3(256), 0, stream>>>(X, Xh, Xl);
        split_wt<<<dim3(48, 16), dim3(256), 0, stream>>>(W, Wth, Wtl);
        qkv_mfma<<<dim3(64, 24), dim3(256), 0, stream>>>(Xh, Xl, Wth, Wtl, Qh, Ql, Kh, Kl, Vt);
        attn_mfma<<<dim3(128, 4), dim3(512), 0, stream>>>(Qh, Ql, Kh, Kl, Vt, mask, out);
    } else if (ws_size >= 3ull * BH * NN * SS * sizeof(float)) {
        float* qkv = (float*)d_ws;
        qkv_kernel<<<dim3(128, 48), dim3(256), 0, stream>>>(X, W, qkv);
        attn_kernel<<<dim3(16, 16, 8), dim3(256), 0, stream>>>(qkv, mask, out);
    }
}

// Round 12
// 405.481 us; speedup vs baseline: 1.0603x; 1.0603x over previous
//
#include <hip/hip_runtime.h>
#include <math.h>

#define BB 8
#define NN 1024
#define DD 1024
#define HH 16
#define SS 64
#define BH (BB*HH)

typedef _Float16 half8 __attribute__((ext_vector_type(8)));
typedef _Float16 half4v __attribute__((ext_vector_type(4)));
typedef float floatx4 __attribute__((ext_vector_type(4)));

#define MFMA16(A, B, C) __builtin_amdgcn_mfma_f32_16x16x32_f16((A), (B), (C), 0, 0, 0)

// async global -> LDS, 16B per lane (dest must be wave-uniform base + lane*16)
__device__ __forceinline__ void gload16(const _Float16* g, _Float16* l) {
    __builtin_amdgcn_global_load_lds(
        (const __attribute__((address_space(1))) void*)g,
        (__attribute__((address_space(3))) void*)l,
        16, 0, 0);
}

// ---------------- Pre-pass: split X into fp16 hi/lo ----------------
__global__ __launch_bounds__(256) void split_x(
    const float* __restrict__ X, _Float16* __restrict__ Xh, _Float16* __restrict__ Xl)
{
    int idx = (blockIdx.x * 256 + threadIdx.x) * 4;
    float4 x4 = *(const float4*)(X + idx);
    float xs[4] = {x4.x, x4.y, x4.z, x4.w};
    half4v h, l;
    #pragma unroll
    for (int i = 0; i < 4; i++) {
        _Float16 hi = (_Float16)xs[i];
        h[i] = hi;
        l[i] = (_Float16)(xs[i] - (float)hi);
    }
    *(half4v*)(Xh + idx) = h;
    *(half4v*)(Xl + idx) = l;
}

// ---------------- Pre-pass: split + transpose W ----------------
__global__ __launch_bounds__(256) void split_wt(
    const float* __restrict__ W, _Float16* __restrict__ Wth, _Float16* __restrict__ Wtl)
{
    __shared__ float tile[64][68];
    const int hc = blockIdx.x, d0 = blockIdx.y * 64;
    const int t = threadIdx.x;
    {
        int i = t >> 2, sq = (t & 3) * 16;
        const float* src = W + ((size_t)hc * DD + d0 + i) * SS + sq;
        #pragma unroll
        for (int u = 0; u < 4; u++) {
            float4 v = *(const float4*)(src + 4 * u);
            tile[i][sq + 4 * u + 0] = v.x; tile[i][sq + 4 * u + 1] = v.y;
            tile[i][sq + 4 * u + 2] = v.z; tile[i][sq + 4 * u + 3] = v.w;
        }
    }
    __syncthreads();
    {
        int s = t >> 2, jq = (t & 3) * 16;
        _Float16 hbuf[16], lbuf[16];
        #pragma unroll
        for (int u = 0; u < 16; u++) {
            float x = tile[jq + u][s];
            _Float16 hi = (_Float16)x;
            hbuf[u] = hi;
            lbuf[u] = (_Float16)(x - (float)hi);
        }
        size_t off = (size_t)hc * SS * DD + (size_t)s * DD + d0 + jq;
        *(half8*)(Wth + off)     = *(half8*)(hbuf);
        *(half8*)(Wth + off + 8) = *(half8*)(hbuf + 8);
        *(half8*)(Wtl + off)     = *(half8*)(lbuf);
        *(half8*)(Wtl + off + 8) = *(half8*)(lbuf + 8);
    }
}

// ---------------- Kernel 1: QKV projection, m97-style LDS-staged GEMM ------
// R11: c-homogeneous blocks. by = (c, head-pair): block computes heads
// {2hp, 2hp+1} for ONE component c. For c==2 (V): outputs are rounded to
// plain fp16 in Vt, and the AlBh term (~2e-4 rms) is below V's fp16
// half-ulp (~7e-4) -> fp16x2 (skip AlBh pass + sAl staging) changes at
// most occasional 1-ulp Vt roundings. Q/K stay exact fp16x3.
// Saves 1/3 MFMA + 1/4 staging on 1/3 of blocks (~-11% qkv MFMA).
__global__ __launch_bounds__(256, 2) void qkv_mfma(
    const _Float16* __restrict__ Xh, const _Float16* __restrict__ Xl,
    const _Float16* __restrict__ Wth, const _Float16* __restrict__ Wtl,
    _Float16* __restrict__ Qh, _Float16* __restrict__ Ql,
    _Float16* __restrict__ Kh, _Float16* __restrict__ Kl,
    _Float16* __restrict__ Vt)
{
    const int flat = blockIdx.y * 64 + blockIdx.x;
    const int swz  = (flat & 7) * 192 + (flat >> 3);
    const int bx = swz & 63;       // token tile (0..63)
    const int by = swz >> 6;       // (c, head-pair) (0..23)
    const int cvar = by % 3;       // component: 0=Q 1=K 2=V (block-uniform)
    const int hp   = by / 3;       // head pair (0..7)
    const int hc_w0 = (2 * hp) * 3 + cvar;   // wave-col 0's panel
    const int r0  = bx * 128;

    const int tid = threadIdx.x;
    const int wave = tid >> 6, lane = tid & 63;
    const int l16 = lane & 15, quad = lane >> 4;
    const int wr = wave >> 1, wc = wave & 1;   // 2x2 wave grid, 64x64 each

    __shared__ _Float16 sAh[128 * 32];   // 8 KB each, 32 KB total
    __shared__ _Float16 sAl[128 * 32];
    __shared__ _Float16 sBh[128 * 32];
    __shared__ _Float16 sBl[128 * 32];

    floatx4 acc[4][4];
    #pragma unroll
    for (int i = 0; i < 4; i++)
        #pragma unroll
        for (int j = 0; j < 4; j++) acc[i][j] = (floatx4){0.f, 0.f, 0.f, 0.f};

    const _Float16* Ab_h = Xh  + (size_t)r0 * DD;
    const _Float16* Ab_l = Xl  + (size_t)r0 * DD;
    const _Float16* Bb_h = Wth + (size_t)hc_w0 * SS * DD;
    const _Float16* Bb_l = Wtl + (size_t)hc_w0 * SS * DD;

    for (int k0 = 0; k0 < DD; k0 += 32) {
        // stage: B rows 0..63 = panel hc_w0, rows 64..127 = panel hc_w0+3
        #pragma unroll
        for (int i = 0; i < 2; i++) {
            const int g = tid + 256 * i;
            const int row = g >> 2, kc = (g & 3) * 8;
            const size_t go = (size_t)row * DD + k0 + kc;
            const size_t bo = go + ((row & 64) ? (size_t)(2 * SS * DD) : 0);
            gload16(Ab_h + go, &sAh[g * 8]);
            if (cvar != 2) gload16(Ab_l + go, &sAl[g * 8]);
            gload16(Bb_h + bo, &sBh[g * 8]);
            gload16(Bb_l + bo, &sBl[g * 8]);
        }
        __syncthreads();

        half8 Ah[4], Al[4], Bh[4], Bl[4];
        #pragma unroll
        for (int t = 0; t < 4; t++) {
            const int ar = wr * 64 + 16 * t + l16;
            const int br = wc * 64 + 16 * t + l16;
            Ah[t] = *(const half8*)&sAh[ar * 32 + quad * 8];
            Bh[t] = *(const half8*)&sBh[br * 32 + quad * 8];
            Bl[t] = *(const half8*)&sBl[br * 32 + quad * 8];
        }
        if (cvar != 2) {
            #pragma unroll
            for (int t = 0; t < 4; t++) {
                const int ar = wr * 64 + 16 * t + l16;
                Al[t] = *(const half8*)&sAl[ar * 32 + quad * 8];
            }
        }
        #pragma unroll
        for (int i = 0; i < 4; i++)
            #pragma unroll
            for (int j = 0; j < 4; j++)
                acc[i][j] = MFMA16(Ah[i], Bh[j], acc[i][j]);
        #pragma unroll
        for (int i = 0; i < 4; i++)
            #pragma unroll
            for (int j = 0; j < 4; j++)
                acc[i][j] = MFMA16(Ah[i], Bl[j], acc[i][j]);
        if (cvar != 2) {
            #pragma unroll
            for (int i = 0; i < 4; i++)
                #pragma unroll
                for (int j = 0; j < 4; j++)
                    acc[i][j] = MFMA16(Al[i], Bh[j], acc[i][j]);
        }
        __syncthreads();
    }

    const int h = 2 * hp + wc;     // this wave's head
    const int c = cvar;
    const int rowbase = r0 + wr * 64;
    if (c == 2) {
        #pragma unroll
        for (int i = 0; i < 4; i++)
            #pragma unroll
            for (int j = 0; j < 4; j++) {
                int tok0 = rowbase + 16 * i + 4 * quad;
                int b = tok0 >> 10, n0 = tok0 & 1023;
                half4v pk;
                #pragma unroll
                for (int r = 0; r < 4; r++) pk[r] = (_Float16)acc[i][j][r];
                *(half4v*)(Vt + ((size_t)(b * HH + h) * SS + 16 * j + l16) * NN + n0) = pk;
            }
    } else {
        _Float16* Ph = (c == 0) ? Qh : Kh;
        _Float16* Pl = (c == 0) ? Ql : Kl;
        #pragma unroll
        for (int i = 0; i < 4; i++)
            #pragma unroll
            for (int j = 0; j < 4; j++)
                #pragma unroll
                for (int r = 0; r < 4; r++) {
                    int tok = rowbase + 16 * i + 4 * quad + r;
                    int b = tok >> 10, n = tok & 1023;
                    float v = acc[i][j][r];
                    _Float16 vh = (_Float16)v;
                    _Float16 vl = (_Float16)(v - (float)vh);
                    size_t off = ((size_t)(b * HH + h) * NN + n) * SS + 16 * j + l16;
                    Ph[off] = vh; Pl[off] = vl;
                }
    }
}

// ---------------- Kernel 2: MFMA flash attention, swapped QK^T -------------
// (R10: 512-thread blocks, 8 waves, grid (128,4); setprio; defer-rescale.
//  attn ~177us per-dispatch, FETCH halved vs 256-thr. Unchanged.)
__global__ __launch_bounds__(512) void attn_mfma(
    const _Float16* __restrict__ Qh, const _Float16* __restrict__ Ql,
    const _Float16* __restrict__ Kh, const _Float16* __restrict__ Kl,
    const _Float16* __restrict__ Vt,
    const float* __restrict__ mask,
    float* __restrict__ out)
{
    const int bh = blockIdx.x, qt = blockIdx.y;   // qt in 0..3
    const int b = bh >> 4, h = bh & 15;
    const int tid = threadIdx.x;
    const int wave = tid >> 6, lane = tid & 63;   // wave in 0..7
    const int l16 = lane & 15, quad = lane >> 4;

    __shared__ float Ms[NN];                 //  4 KB
    __shared__ _Float16 KhS[64 * 64];        //  8 KB
    __shared__ _Float16 KlS[64 * 64];        //  8 KB
    __shared__ _Float16 VS [64 * 64];        //  8 KB
    __shared__ _Float16 Plds[8][32][72];     // 36 KB   total 64 KB -> 2 blk/CU

    *(float2*)&Ms[tid * 2] = *(const float2*)(mask + b * NN + tid * 2);

    // granule g = tid in [0,512): row=g>>3, slot col=g&7,
    // source col c=(g&7)^(row&7)  (XOR swizzle realized by permuting source)
    half8 G[3];
    auto stage_load = [&](int kt_) {
        int g = tid;
        int row = g >> 3;
        int c = (g & 7) ^ (row & 7);
        size_t ko = ((size_t)bh * NN + kt_ * 64 + row) * SS + c * 8;
        G[0] = *(const half8*)(Kh + ko);
        G[1] = *(const half8*)(Kl + ko);
        G[2] = *(const half8*)(Vt + ((size_t)bh * SS + row) * NN
                               + (size_t)kt_ * 64 + c * 8);
    };
    auto stage_store = [&]() {
        int g = tid;
        *(half8*)&KhS[g * 8] = G[0];
        *(half8*)&KlS[g * 8] = G[1];
        *(half8*)&VS [g * 8] = G[2];
    };

    stage_load(0);
    stage_store();
    __syncthreads();     // Ms + buf ready

    const int qrow0 = qt * 256 + wave * 32;
    half8 Aqh[2][2], Aql[2][2];
    #pragma unroll
    for (int g = 0; g < 2; g++) {
        const size_t qbase = ((size_t)bh * NN + qrow0 + 16 * g + l16) * SS + quad * 8;
        Aqh[g][0] = *(const half8*)(Qh + qbase);
        Aqh[g][1] = *(const half8*)(Qh + qbase + 32);
        Aql[g][0] = *(const half8*)(Ql + qbase);
        Aql[g][1] = *(const half8*)(Ql + qbase + 32);
    }

    // per-lane state for q-row = qrow0 + 16*g + l16
    float qm[2], m_old[2], l_sum[2];
    floatx4 accO[2][4];
    #pragma unroll
    for (int g = 0; g < 2; g++) {
        qm[g] = Ms[qrow0 + 16 * g + l16];
        m_old[g] = -3.0e38f;
        l_sum[g] = 0.f;
        #pragma unroll
        for (int j = 0; j < 4; j++) accO[g][j] = (floatx4){0.f, 0.f, 0.f, 0.f};
    }

    const int sw = l16 & 7;

    for (int kt = 0; kt < 16; kt++) {
        if (kt < 15) stage_load(kt + 1);   // in flight during compute below

        // ---- S^T = K Q^T (fp16x3): same frags, swapped operand roles ----
        floatx4 accS[2][4];
        #pragma unroll
        for (int g = 0; g < 2; g++)
            #pragma unroll
            for (int jt = 0; jt < 4; jt++) accS[g][jt] = (floatx4){0.f, 0.f, 0.f, 0.f};
        __builtin_amdgcn_s_setprio(1);
        #pragma unroll
        for (int jt = 0; jt < 4; jt++) {
            const int rowK = jt * 16 + l16;
            const _Float16* krh = &KhS[rowK * 64];
            const _Float16* krl = &KlS[rowK * 64];
            half8 Bh0 = *(const half8*)&krh[((quad    ) ^ sw) * 8];
            half8 Bh1 = *(const half8*)&krh[((quad + 4) ^ sw) * 8];
            half8 Bl0 = *(const half8*)&krl[((quad    ) ^ sw) * 8];
            half8 Bl1 = *(const half8*)&krl[((quad + 4) ^ sw) * 8];
            #pragma unroll
            for (int g = 0; g < 2; g++) {
                accS[g][jt] = MFMA16(Bh0, Aqh[g][0], accS[g][jt]);
                accS[g][jt] = MFMA16(Bh1, Aqh[g][1], accS[g][jt]);
                accS[g][jt] = MFMA16(Bl0, Aqh[g][0], accS[g][jt]);
                accS[g][jt] = MFMA16(Bl1, Aqh[g][1], accS[g][jt]);
                accS[g][jt] = MFMA16(Bh0, Aql[g][0], accS[g][jt]);
                accS[g][jt] = MFMA16(Bh1, Aql[g][1], accS[g][jt]);
            }
        }
        __builtin_amdgcn_s_setprio(0);
        // accS[g][jt][r] = S[q = qrow0+16g+l16][k = kt*64 + jt*16 + quad*4 + r]

        // ---- literal fp32 mask penalty (k-cols contiguous: float4 loads) ----
        float km[4][4];
        #pragma unroll
        for (int jt = 0; jt < 4; jt++) {
            float4 k4 = *(const float4*)&Ms[kt * 64 + jt * 16 + quad * 4];
            km[jt][0] = k4.x; km[jt][1] = k4.y; km[jt][2] = k4.z; km[jt][3] = k4.w;
        }
        #pragma unroll
        for (int g = 0; g < 2; g++)
            #pragma unroll
            for (int jt = 0; jt < 4; jt++)
                #pragma unroll
                for (int r = 0; r < 4; r++)
                    accS[g][jt][r] -= 1.0e8f * (1.0f - qm[g] * km[jt][r]);

        // ---- online softmax: lane-local row, 2 shuffles per reduce ----
        #pragma unroll
        for (int g = 0; g < 2; g++) {
            float a0 = fmaxf(fmaxf(accS[g][0][0], accS[g][0][1]),
                             fmaxf(accS[g][0][2], accS[g][0][3]));
            float a1 = fmaxf(fmaxf(accS[g][1][0], accS[g][1][1]),
                             fmaxf(accS[g][1][2], accS[g][1][3]));
            float a2 = fmaxf(fmaxf(accS[g][2][0], accS[g][2][1]),
                             fmaxf(accS[g][2][2], accS[g][2][3]));
            float a3 = fmaxf(fmaxf(accS[g][3][0], accS[g][3][1]),
                             fmaxf(accS[g][3][2], accS[g][3][3]));
            float mt = fmaxf(fmaxf(a0, a1), fmaxf(a2, a3));
            mt = fmaxf(mt, __shfl_xor(mt, 16, 64));
            mt = fmaxf(mt, __shfl_xor(mt, 32, 64));
            float mn = fmaxf(m_old[g], mt);

            float sj[4];
            #pragma unroll
            for (int jt = 0; jt < 4; jt++) {
                float p0 = __expf(accS[g][jt][0] - mn);
                float p1 = __expf(accS[g][jt][1] - mn);
                float p2 = __expf(accS[g][jt][2] - mn);
                float p3 = __expf(accS[g][jt][3] - mn);
                accS[g][jt][0] = p0; accS[g][jt][1] = p1;
                accS[g][jt][2] = p2; accS[g][jt][3] = p3;
                sj[jt] = (p0 + p1) + (p2 + p3);
            }
            float ls = (sj[0] + sj[1]) + (sj[2] + sj[3]);
            ls += __shfl_xor(ls, 16, 64);
            ls += __shfl_xor(ls, 32, 64);

            // defer-rescale: if no lane's max grew, mn == m_old for every
            // lane, alpha == __expf(0) == 1.0 exactly -> skip is bit-identical.
            if (__any(mt > m_old[g])) {
                float alpha = __expf(m_old[g] - mn);
                m_old[g] = mn;
                l_sum[g] = l_sum[g] * alpha + ls;
                float alphaO[4];
                #pragma unroll
                for (int r = 0; r < 4; r++)
                    alphaO[r] = __shfl(alpha, quad * 4 + r, 64);
                #pragma unroll
                for (int j = 0; j < 4; j++)
                    #pragma unroll
                    for (int r = 0; r < 4; r++)
                        accO[g][j][r] *= alphaO[r];
            } else {
                l_sum[g] = l_sum[g] + ls;
            }

            // P -> LDS: k-contiguous half4v packs, row = q, col = k
            #pragma unroll
            for (int jt = 0; jt < 4; jt++) {
                half4v pk;
                #pragma unroll
                for (int r = 0; r < 4; r++) pk[r] = (_Float16)accS[g][jt][r];
                *(half4v*)&Plds[wave][16 * g + l16][jt * 16 + quad * 4] = pk;
            }
        }

        // ---- O += P V (A = P rows q, k-chunk quad*8; B = V from LDS) ----
        __builtin_amdgcn_s_setprio(1);
        #pragma unroll
        for (int ks = 0; ks < 2; ks++) {
            half8 Ap[2];
            #pragma unroll
            for (int g = 0; g < 2; g++)
                Ap[g] = *(const half8*)&Plds[wave][16 * g + l16][ks * 32 + quad * 8];
            #pragma unroll
            for (int j = 0; j < 4; j++) {
                half8 Bv = *(const half8*)&VS[(j * 16 + l16) * 64
                                              + (((ks * 4 + quad) ^ sw) * 8)];
                #pragma unroll
                for (int g = 0; g < 2; g++)
                    accO[g][j] = MFMA16(Ap[g], Bv, accO[g][j]);
            }
        }
        __builtin_amdgcn_s_setprio(0);

        if (kt < 15) {
            __syncthreads();     // all waves done reading KhS/KlS/VS
            stage_store();       // waits in-flight loads, fills buf
            __syncthreads();     // buf ready
        }
    }

    // ---- epilogue: out[b, n, s*16 + h]; l_sum lives at lane l16 = q ----
    #pragma unroll
    for (int g = 0; g < 2; g++) {
        float inv[4];
        #pragma unroll
        for (int r = 0; r < 4; r++)
            inv[r] = 1.f / __shfl(l_sum[g], quad * 4 + r, 64);
        #pragma unroll
        for (int r = 0; r < 4; r++) {
            int qrow = qrow0 + 16 * g + quad * 4 + r;
            #pragma unroll
            for (int j = 0; j < 4; j++)
                out[((size_t)(b * NN + qrow)) * (SS * HH) + (j * 16 + l16) * HH + h] =
                    accO[g][j][r] * inv[r];
        }
    }
}

// ================= fp32 fallback path (R2, known-good) =================
__global__ __launch_bounds__(256) void qkv_kernel(
    const float* __restrict__ X, const float* __restrict__ W, float* __restrict__ qkv)
{
    const int ttile = blockIdx.x;
    const int hc    = blockIdx.y;
    const int h     = hc / 3, c = hc % 3;
    const int tid = threadIdx.x;
    const int tx = tid & 15, ty = tid >> 4;
    __shared__ float As[32][68];
    __shared__ float Bs[32][68];
    const float* Wb = W + (size_t)hc * DD * SS;
    const int row0 = ttile * 64;
    float acc[4][4];
    #pragma unroll
    for (int i = 0; i < 4; i++)
        #pragma unroll
        for (int j = 0; j < 4; j++) acc[i][j] = 0.f;
    for (int k0 = 0; k0 < DD; k0 += 32) {
        #pragma unroll
        for (int l = 0; l < 2; l++) {
            int i = tid + l * 256;
            int r = i >> 3;
            int kq = (i & 7) * 4;
            float4 x4 = *(const float4*)(X + (size_t)(row0 + r) * DD + k0 + kq);
            As[kq + 0][r] = x4.x; As[kq + 1][r] = x4.y;
            As[kq + 2][r] = x4.z; As[kq + 3][r] = x4.w;
        }
        #pragma unroll
        for (int l = 0; l < 2; l++) {
            int i = tid + l * 256;
            int kr = i >> 4;
            int sq = (i & 15) * 4;
            *(float4*)&Bs[kr][sq] = *(const float4*)(Wb + (size_t)(k0 + kr) * SS + sq);
        }
        __syncthreads();
        #pragma unroll
        for (int kk = 0; kk < 32; kk++) {
            float4 a4 = *(const float4*)&As[kk][ty * 4];
            float4 b4 = *(const float4*)&Bs[kk][tx * 4];
            float a[4] = {a4.x, a4.y, a4.z, a4.w};
            float bb[4] = {b4.x, b4.y, b4.z, b4.w};
            #pragma unroll
            for (int i = 0; i < 4; i++)
                #pragma unroll
                for (int j = 0; j < 4; j++)
                    acc[i][j] = fmaf(a[i], bb[j], acc[i][j]);
        }
        __syncthreads();
    }
    float* outp = qkv + (size_t)c * BH * NN * SS;
    #pragma unroll
    for (int i = 0; i < 4; i++) {
        int tg = row0 + ty * 4 + i;
        int b = tg >> 10, n = tg & 1023;
        float4 v4 = make_float4(acc[i][0], acc[i][1], acc[i][2], acc[i][3]);
        *(float4*)(outp + ((size_t)(b * HH + h) * NN + n) * SS + tx * 4) = v4;
    }
}

__global__ __launch_bounds__(256) void attn_kernel(
    const float* __restrict__ qkv,
    const float* __restrict__ mask,
    float* __restrict__ out)
{
    const int qt = blockIdx.x, h = blockIdx.y, b = blockIdx.z;
    const int tid = threadIdx.x;
    const int tx = tid & 15, ty = tid >> 4;
    const int bh = b * HH + h;
    const float* Q = qkv + (size_t)bh * NN * SS;
    const float* K = qkv + (size_t)BH * NN * SS + (size_t)bh * NN * SS;
    const float* V = qkv + 2 * (size_t)BH * NN * SS + (size_t)bh * NN * SS;

    __shared__ float QsT[64][68];
    __shared__ float KsT[64][68];
    __shared__ float Vs [64][68];
    __shared__ float PsT[64][68];
    __shared__ float Ms[NN];

    {
        float4 mm = *(const float4*)(mask + b * NN + tid * 4);
        *(float4*)&Ms[tid * 4] = mm;
    }
    #pragma unroll
    for (int l = 0; l < 4; l++) {
        int i = tid + l * 256;
        int r = i >> 4, sq = (i & 15) * 4;
        float4 x4 = *(const float4*)(Q + (size_t)(qt * 64 + r) * SS + sq);
        QsT[sq + 0][r] = x4.x; QsT[sq + 1][r] = x4.y;
        QsT[sq + 2][r] = x4.z; QsT[sq + 3][r] = x4.w;
    }
    __syncthreads();

    float m_old[4], l_sum[4], O[4][4], qm[4];
    #pragma unroll
    for (int i = 0; i < 4; i++) {
        qm[i] = Ms[qt * 64 + ty * 4 + i];
        m_old[i] = -3.0e38f; l_sum[i] = 0.f;
        #pragma unroll
        for (int j = 0; j < 4; j++) O[i][j] = 0.f;
    }

    for (int kt = 0; kt < 16; kt++) {
        #pragma unroll
        for (int l = 0; l < 4; l++) {
            int i = tid + l * 256;
            int r = i >> 4, sq = (i & 15) * 4;
            float4 k4 = *(const float4*)(K + (size_t)(kt * 64 + r) * SS + sq);
            KsT[sq + 0][r] = k4.x; KsT[sq + 1][r] = k4.y;
            KsT[sq + 2][r] = k4.z; KsT[sq + 3][r] = k4.w;
            float4 v4 = *(const float4*)(V + (size_t)(kt * 64 + r) * SS + sq);
            *(float4*)&Vs[r][sq] = v4;
        }
        __syncthreads();

        float sc[4][4];
        #pragma unroll
        for (int i = 0; i < 4; i++)
            #pragma unroll
            for (int j = 0; j < 4; j++) sc[i][j] = 0.f;
        #pragma unroll 8
        for (int s = 0; s < 64; s++) {
            float4 a4 = *(const float4*)&QsT[s][ty * 4];
            float4 b4 = *(const float4*)&KsT[s][tx * 4];
            float a[4] = {a4.x, a4.y, a4.z, a4.w};
            float bb[4] = {b4.x, b4.y, b4.z, b4.w};
            #pragma unroll
            for (int i = 0; i < 4; i++)
                #pragma unroll
                for (int j = 0; j < 4; j++)
                    sc[i][j] = fmaf(a[i], bb[j], sc[i][j]);
        }
        float km[4];
        #pragma unroll
        for (int j = 0; j < 4; j++) km[j] = Ms[kt * 64 + tx * 4 + j];
        #pragma unroll
        for (int i = 0; i < 4; i++)
            #pragma unroll
            for (int j = 0; j < 4; j++) {
                float pen = 1.0e8f * (1.0f - qm[i] * km[j]);
                sc[i][j] = sc[i][j] - pen;
            }

        #pragma unroll
        for (int i = 0; i < 4; i++) {
            float mt = fmaxf(fmaxf(sc[i][0], sc[i][1]), fmaxf(sc[i][2], sc[i][3]));
            #pragma unroll
            for (int off = 1; off < 16; off <<= 1)
                mt = fmaxf(mt, __shfl_xor(mt, off, 64));
            float mn = fmaxf(m_old[i], mt);
            float alpha = __expf(m_old[i] - mn);
            float p[4];
            #pragma unroll
            for (int j = 0; j < 4; j++) p[j] = __expf(sc[i][j] - mn);
            float ls = (p[0] + p[1]) + (p[2] + p[3]);
            #pragma unroll
            for (int off = 1; off < 16; off <<= 1)
                ls += __shfl_xor(ls, off, 64);
            l_sum[i] = l_sum[i] * alpha + ls;
            m_old[i] = mn;
            #pragma unroll
            for (int j = 0; j < 4; j++) {
                O[i][j] *= alpha;
                PsT[tx * 4 + j][ty * 4 + i] = p[j];
            }
        }
        __syncthreads();

        #pragma unroll 8
        for (int kj = 0; kj < 64; kj++) {
            float4 p4 = *(const float4*)&PsT[kj][ty * 4];
            float4 v4 = *(const float4*)&Vs[kj][tx * 4];
            float p[4] = {p4.x, p4.y, p4.z, p4.w};
            float vv[4] = {v4.x, v4.y, v4.z, v4.w};
            #pragma unroll
            for (int i = 0; i < 4; i++)
                #pragma unroll
                for (int j = 0; j < 4; j++)
                    O[i][j] = fmaf(p[i], vv[j], O[i][j]);
        }
        __syncthreads();
    }

    #pragma unroll
    for (int i = 0; i < 4; i++) {
        int qrow = qt * 64 + ty * 4 + i;
        float inv = 1.f / l_sum[i];
        #pragma unroll
        for (int j = 0; j < 4; j++) {
            int s = tx * 4 + j;
            out[((size_t)(b * NN + qrow)) * (SS * HH) + s * HH + h] = O[i][j] * inv;
        }
    }
}

extern "C" void kernel_launch(void* const* d_in, const int* in_sizes, int n_in,
                              void* d_out, int out_size, void* d_ws, size_t ws_size,
                              hipStream_t stream) {
    const float* X    = (const float*)d_in[0];   // [8,1024,1024]
    const float* mask = (const float*)d_in[1];   // [8,1024]
    const float* W    = (const float*)d_in[2];   // [16,3,1024,64]
    float* out = (float*)d_out;

    const size_t x_elems  = (size_t)BB * NN * DD;       // 8,388,608
    const size_t w_elems  = (size_t)HH * 3 * SS * DD;   // 3,145,728
    const size_t qk_elems = (size_t)BH * NN * SS;       // 8,388,608
    const size_t need_fast = (2 * x_elems + 2 * w_elems + 5 * qk_elems) * sizeof(_Float16); // ~130 MB

    if (ws_size >= need_fast) {
        _Float16* Xh  = (_Float16*)d_ws;
        _Float16* Xl  = Xh  + x_elems;
        _Float16* Wth = Xl  + x_elems;
        _Float16* Wtl = Wth + w_elems;
        _Float16* Qh  = Wtl + w_elems;
        _Float16* Ql  = Qh  + qk_elems;
        _Float16* Kh  = Ql  + qk_elems;
        _Float16* Kl  = Kh  + qk_elems;
        _Float16* Vt  = Kl  + qk_elems;

        split_x<<<dim3((unsigned)(x_elems / 1024)), dim3(256), 0, stream>>>(X, Xh, Xl);
        split_wt<<<dim3(48, 16), dim3(256), 0, stream>>>(W, Wth, Wtl);
        qkv_mfma<<<dim3(64, 24), dim3(256), 0, stream>>>(Xh, Xl, Wth, Wtl, Qh, Ql, Kh, Kl, Vt);
        attn_mfma<<<dim3(128, 4), dim3(512), 0, stream>>>(Qh, Ql, Kh, Kl, Vt, mask, out);
    } else if (ws_size >= 3ull * BH * NN * SS * sizeof(float)) {
        float* qkv = (float*)d_ws;
        qkv_kernel<<<dim3(128, 48), dim3(256), 0, stream>>>(X, W, qkv);
        attn_kernel<<<dim3(16, 16, 8), dim3(256), 0, stream>>>(qkv, mask, out);
    }
}